// Round 13
// baseline (635.791 us; speedup 1.0000x reference)
//
#include <hip/hip_runtime.h>

constexpr int F  = 128;   // input feature dim
constexpr int H1 = 256;
constexpr int H2 = 128;
constexpr int C  = 40;

using f32x4 = __attribute__((ext_vector_type(4))) float;
using f16x8 = __attribute__((ext_vector_type(8))) _Float16;
using f16x2 = __attribute__((ext_vector_type(2))) _Float16;

__device__ __forceinline__ float wave_sum64(float v) {
#pragma unroll
    for (int off = 32; off > 0; off >>= 1) v += __shfl_xor(v, off, 64);
    return v;
}

// ---------------------------------------------------------------------------
// Weight prep: transpose + fp16-convert W1, W2, Wc into workspace.
// ---------------------------------------------------------------------------
__global__ __launch_bounds__(256) void prep_weights(
    const float* __restrict__ W1, const float* __restrict__ W2,
    const float* __restrict__ Wc,
    _Float16* __restrict__ W1t, _Float16* __restrict__ W2t,
    _Float16* __restrict__ Wct)
{
    const int i = blockIdx.x * 256 + threadIdx.x;
    if (i < H1 * F) {
        const int j = i >> 7, f = i & 127;
        W1t[i] = (_Float16)W1[(size_t)f * H1 + j];
    }
    if (i < H2 * H1) {
        const int j = i >> 8, k = i & 255;
        W2t[i] = (_Float16)W2[(size_t)k * H2 + j];
    }
    if (i < 48 * F) {
        const int c = i >> 7, k = i & 127;
        Wct[i] = (c < C) ? (_Float16)Wc[(size_t)k * C + c] : (_Float16)0.f;
    }
}

// ---------------------------------------------------------------------------
// Counting sort of edges by segment: hist -> 3-pass scan -> scatter.
// ---------------------------------------------------------------------------
__global__ __launch_bounds__(256) void k_hist(
    const int* __restrict__ seg, int* __restrict__ hist, int E)
{
    const int e = blockIdx.x * 256 + threadIdx.x;
    if (e < E) atomicAdd(&hist[seg[e]], 1);
}

__global__ __launch_bounds__(256) void k_scan1(
    const int* __restrict__ hist, int* __restrict__ bsum, int N)
{
    __shared__ int s[256];
    const int t = threadIdx.x;
    const int i = blockIdx.x * 256 + t;
    s[t] = (i < N) ? hist[i] : 0;
    __syncthreads();
#pragma unroll
    for (int off = 128; off > 0; off >>= 1) {
        if (t < off) s[t] += s[t + off];
        __syncthreads();
    }
    if (t == 0) bsum[blockIdx.x] = s[0];
}

__global__ __launch_bounds__(256) void k_scan2(int* __restrict__ bsum, int B)
{
    __shared__ int s[256];
    const int t = threadIdx.x;
    const int v = (t < B) ? bsum[t] : 0;
    s[t] = v;
    __syncthreads();
#pragma unroll
    for (int off = 1; off < 256; off <<= 1) {
        const int u = (t >= off) ? s[t - off] : 0;
        __syncthreads();
        s[t] += u;
        __syncthreads();
    }
    if (t < B) bsum[t] = s[t] - v;   // exclusive block offsets
}

__global__ __launch_bounds__(256) void k_scan3(
    const int* __restrict__ hist, const int* __restrict__ bsum,
    int* __restrict__ start, int* __restrict__ cursor, int N, int E)
{
    __shared__ int s[256];
    const int t = threadIdx.x;
    const int i = blockIdx.x * 256 + t;
    const int v = (i < N) ? hist[i] : 0;
    s[t] = v;
    __syncthreads();
#pragma unroll
    for (int off = 1; off < 256; off <<= 1) {
        const int u = (t >= off) ? s[t - off] : 0;
        __syncthreads();
        s[t] += u;
        __syncthreads();
    }
    if (i < N) {
        start[i]  = bsum[blockIdx.x] + s[t] - v;
        cursor[i] = 0;
    }
    if (i == 0) start[N] = E;
}

__global__ __launch_bounds__(256) void k_scatter(
    const int* __restrict__ seg, const int* __restrict__ start,
    int* __restrict__ cursor, int* __restrict__ ord, int E)
{
    const int e = blockIdx.x * 256 + threadIdx.x;
    if (e < E) {
        const int s = seg[e];
        const int r = atomicAdd(&cursor[s], 1);
        ord[start[s] + r] = e;
    }
}

// ---------------------------------------------------------------------------
// Edge kernel v13: v9 structure with 48-row tiles (4 waves x 12-row agg
// windows; MFMA row-tiles stay 16 x 3, col-split across waves).
// LDS 38.4 KB -> 4 blocks/CU (was 51.2 KB -> 3).
// NOTE (r10/r11): do NOT hoist more A/B into registers — spills at ~84 VGPR.
// ---------------------------------------------------------------------------
__global__ __launch_bounds__(256, 4) void edge_kernel13(
    const float* __restrict__ nbx, const int* __restrict__ seg,
    const int* __restrict__ ord, const int* __restrict__ start,
    const _Float16* __restrict__ W1t, const float* __restrict__ b1,
    const _Float16* __restrict__ W2t, const float* __restrict__ b2,
    float* __restrict__ Sx, float* __restrict__ S2, float* __restrict__ S4,
    int E)
{
    __shared__ _Float16 s_nb[48][136];   // nb, later n_h2  (13.1 KB)
    __shared__ _Float16 s_nh[48][264];   // n_h             (25.3 KB)

    const int tid   = threadIdx.x;
    const int lane  = tid & 63;
    const int w     = tid >> 6;
    const int wrow0 = w * 12;
    const int mrow  = lane & 15;
    const int kgrp  = lane >> 4;
    const int base  = blockIdx.x * 96;

    // ---- prologue: meta + gathers for both tiles ----
    int edg[2], sv[2], fl[2];
    float va[2][12][2];
#pragma unroll
    for (int t = 0; t < 2; ++t) {
        const int wbase = base + t * 48 + wrow0;
        const int p     = wbase + mrow;
        const bool pin  = (mrow < 12) && (p < E);
        edg[t] = pin ? ord[p] : 0;
        sv[t]  = pin ? seg[edg[t]] : -1;
        fl[t]  = 0;
        if (pin) {
            const int s0 = start[sv[t]], s1 = start[sv[t] + 1];
            fl[t] = (s0 >= wbase) && (s1 <= wbase + 12);
        }
#pragma unroll
        for (int r = 0; r < 12; ++r) {
            const int er = __shfl(edg[t], r);
            const bool v = (wbase + r < E);
            va[t][r][0] = v ? nbx[(size_t)er * F + lane] : 0.f;
            va[t][r][1] = v ? nbx[(size_t)er * F + 64 + lane] : 0.f;
        }
    }

#pragma unroll
    for (int t = 0; t < 2; ++t) {
        // ---- l2norm + LDS store ----
#pragma unroll
        for (int r = 0; r < 12; ++r) {
            const float ss = wave_sum64(va[t][r][0] * va[t][r][0] +
                                        va[t][r][1] * va[t][r][1]);
            const float sc = 1.0f / fmaxf(sqrtf(ss), 1e-12f);
            va[t][r][0] *= sc; va[t][r][1] *= sc;
            s_nb[wrow0 + r][lane]      = (_Float16)va[t][r][0];
            s_nb[wrow0 + r][64 + lane] = (_Float16)va[t][r][1];
        }

        // ---- Sx agg from registers ----
        {
            float a0 = 0.f, a1v = 0.f;
            int cur = __shfl(sv[t], 0);
            int cf  = __shfl(fl[t], 0);
#pragma unroll
            for (int r = 0; r < 12; ++r) {
                a0 += va[t][r][0]; a1v += va[t][r][1];
                const int nxt = (r < 11) ? __shfl(sv[t], r + 1) : -2;
                if (nxt != cur) {
                    if (cur >= 0) {
                        float* d = &Sx[(size_t)cur * F + lane];
                        if (cf) { d[0] = a0; d[64] = a1v; }
                        else    { atomicAdd(d, a0); atomicAdd(d + 64, a1v); }
                    }
                    a0 = 0.f; a1v = 0.f; cur = nxt;
                    if (r < 11) cf = __shfl(fl[t], r + 1);
                }
            }
        }
        __syncthreads();   // (1) A-tile ready

        // ---- GEMM1: cols [w*64,(w+1)*64); A re-read from s_nb ----
        {
            const int colbase = w * 64 + mrow;
            float bj1[4];
#pragma unroll
            for (int ct = 0; ct < 4; ++ct) bj1[ct] = b1[colbase + ct * 16];

            f16x8 b[4], bn[4];
#pragma unroll
            for (int kk = 0; kk < 4; ++kk)
                b[kk] = *(const f16x8*)&W1t[(size_t)colbase * F + kk * 32 + kgrp * 8];

#pragma unroll
            for (int ct = 0; ct < 4; ++ct) {
                const int col = colbase + ct * 16;
                if (ct < 3) {
#pragma unroll
                    for (int kk = 0; kk < 4; ++kk)
                        bn[kk] = *(const f16x8*)&W1t[(size_t)(col + 16) * F + kk * 32 + kgrp * 8];
                }
                f32x4 acc[3];
#pragma unroll
                for (int m = 0; m < 3; ++m) acc[m] = (f32x4){0.f, 0.f, 0.f, 0.f};
                __builtin_amdgcn_s_setprio(1);
#pragma unroll
                for (int m = 0; m < 3; ++m) {
                    f16x8 a[4];
#pragma unroll
                    for (int kk = 0; kk < 4; ++kk)
                        a[kk] = *(const f16x8*)&s_nb[m * 16 + mrow][kk * 32 + kgrp * 8];
#pragma unroll
                    for (int kk = 0; kk < 4; ++kk)
                        acc[m] = __builtin_amdgcn_mfma_f32_16x16x32_f16(a[kk], b[kk], acc[m], 0, 0, 0);
                }
                __builtin_amdgcn_s_setprio(0);
#pragma unroll
                for (int m = 0; m < 3; ++m)
#pragma unroll
                    for (int q = 0; q < 4; ++q)
                        s_nh[m * 16 + kgrp * 4 + q][col] = (_Float16)(acc[m][q] + bj1[ct]);
#pragma unroll
                for (int kk = 0; kk < 4; ++kk) b[kk] = bn[kk];
            }
        }
        __syncthreads();   // (2) n_h ready

        // ---- S2 agg (own 12-row window of s_nh; relu on read) ----
#pragma unroll
        for (int half = 0; half < 2; ++half) {
            const int c0 = half * 128 + 2 * lane;
            float a0 = 0.f, a1v = 0.f;
            int cur = __shfl(sv[t], 0);
            int cf  = __shfl(fl[t], 0);
#pragma unroll
            for (int r = 0; r < 12; ++r) {
                const f16x2 pv = *(const f16x2*)&s_nh[wrow0 + r][c0];
                a0  += fmaxf((float)pv[0], 0.f);
                a1v += fmaxf((float)pv[1], 0.f);
                const int nxt = (r < 11) ? __shfl(sv[t], r + 1) : -2;
                if (nxt != cur) {
                    if (cur >= 0) {
                        float* d = &S2[(size_t)cur * H1 + c0];
                        if (cf) { *(float2*)d = make_float2(a0, a1v); }
                        else    { atomicAdd(d, a0); atomicAdd(d + 1, a1v); }
                    }
                    a0 = 0.f; a1v = 0.f; cur = nxt;
                    if (r < 11) cf = __shfl(fl[t], r + 1);
                }
            }
        }

        // ---- GEMM2: cols [w*32,(w+1)*32); A from s_nh; n_h2 -> s_nb ----
#pragma unroll
        for (int ct = 0; ct < 2; ++ct) {
            const int col = w * 32 + ct * 16 + mrow;
            const float bj = b2[col];
            f16x8 b[8];
#pragma unroll
            for (int k0 = 0; k0 < 8; ++k0)
                b[k0] = *(const f16x8*)&W2t[(size_t)col * H1 + k0 * 32 + kgrp * 8];
            f32x4 acc[3];
#pragma unroll
            for (int m = 0; m < 3; ++m) acc[m] = (f32x4){0.f, 0.f, 0.f, 0.f};
            __builtin_amdgcn_s_setprio(1);
#pragma unroll
            for (int m = 0; m < 3; ++m) {
                f16x8 a[8];
#pragma unroll
                for (int k0 = 0; k0 < 8; ++k0)
                    a[k0] = *(const f16x8*)&s_nh[m * 16 + mrow][k0 * 32 + kgrp * 8];
#pragma unroll
                for (int k0 = 0; k0 < 8; ++k0)
                    acc[m] = __builtin_amdgcn_mfma_f32_16x16x32_f16(a[k0], b[k0], acc[m], 0, 0, 0);
            }
            __builtin_amdgcn_s_setprio(0);
#pragma unroll
            for (int m = 0; m < 3; ++m)
#pragma unroll
                for (int q = 0; q < 4; ++q)
                    s_nb[m * 16 + kgrp * 4 + q][col] = (_Float16)(acc[m][q] + bj);
        }
        __syncthreads();   // (3) n_h2 ready

        // ---- S4 agg (own 12-row window of s_nb; relu on read) ----
        {
            const int c0 = 2 * lane;
            float a0 = 0.f, a1v = 0.f;
            int cur = __shfl(sv[t], 0);
            int cf  = __shfl(fl[t], 0);
#pragma unroll
            for (int r = 0; r < 12; ++r) {
                const f16x2 pv = *(const f16x2*)&s_nb[wrow0 + r][c0];
                a0  += fmaxf((float)pv[0], 0.f);
                a1v += fmaxf((float)pv[1], 0.f);
                const int nxt = (r < 11) ? __shfl(sv[t], r + 1) : -2;
                if (nxt != cur) {
                    if (cur >= 0) {
                        float* d = &S4[(size_t)cur * H2 + c0];
                        if (cf) { *(float2*)d = make_float2(a0, a1v); }
                        else    { atomicAdd(d, a0); atomicAdd(d + 1, a1v); }
                    }
                    a0 = 0.f; a1v = 0.f; cur = nxt;
                    if (r < 11) cf = __shfl(fl[t], r + 1);
                }
            }
        }
        __syncthreads();   // (4) buffers free for next tile
    }
}

// ---------------------------------------------------------------------------
// Node kernel v8 (unchanged): direct-global A-frags, MFMA, zero barriers.
// ---------------------------------------------------------------------------
__global__ __launch_bounds__(256, 2) void node_kernel8(
    const float* __restrict__ x,
    const _Float16* __restrict__ W1t, const float* __restrict__ b1,
    const _Float16* __restrict__ W2t, const float* __restrict__ b2,
    const _Float16* __restrict__ Wct, const float* __restrict__ bc,
    const float* __restrict__ Sx, const float* __restrict__ S2,
    const float* __restrict__ S4, const int* __restrict__ start,
    float* __restrict__ out, int N)
{
    __shared__ _Float16 s_a[4][32][264];

    const int tid  = threadIdx.x;
    const int lane = tid & 63;
    const int w    = tid >> 6;
    const int n0   = blockIdx.x * 64 + w * 16;
    const int mrow = lane & 15;
    const int kgrp = lane >> 4;

    const int  n_row = n0 + mrow;
    const bool rin   = (n_row < N);
    float xv[4][8], sxv[4][8];
#pragma unroll
    for (int kk = 0; kk < 4; ++kk) {
        const size_t off = (size_t)n_row * F + kk * 32 + kgrp * 8;
        float4 a0 = {0.f,0.f,0.f,0.f}, a1 = a0, b0 = a0, b1 = a0;
        if (rin) {
            a0 = *(const float4*)&x[off];
            a1 = *(const float4*)&x[off + 4];
            b0 = *(const float4*)&Sx[off];
            b1 = *(const float4*)&Sx[off + 4];
        }
        xv[kk][0]=a0.x; xv[kk][1]=a0.y; xv[kk][2]=a0.z; xv[kk][3]=a0.w;
        xv[kk][4]=a1.x; xv[kk][5]=a1.y; xv[kk][6]=a1.z; xv[kk][7]=a1.w;
        sxv[kk][0]=b0.x; sxv[kk][1]=b0.y; sxv[kk][2]=b0.z; sxv[kk][3]=b0.w;
        sxv[kk][4]=b1.x; sxv[kk][5]=b1.y; sxv[kk][6]=b1.z; sxv[kk][7]=b1.w;
    }

    float ss = 0.f;
#pragma unroll
    for (int kk = 0; kk < 4; ++kk)
#pragma unroll
        for (int j = 0; j < 8; ++j) ss += xv[kk][j] * xv[kk][j];
    ss += __shfl_xor(ss, 16);
    ss += __shfl_xor(ss, 32);
    const float sc = 1.0f / fmaxf(sqrtf(ss), 1e-12f);

    f16x8 aA[2][4];
#pragma unroll
    for (int kk = 0; kk < 4; ++kk)
#pragma unroll
        for (int j = 0; j < 8; ++j) {
            aA[0][kk][j] = (_Float16)(xv[kk][j] * sc);
            aA[1][kk][j] = (_Float16)sxv[kk][j];
        }

    float cntq[4];
#pragma unroll
    for (int q = 0; q < 4; ++q) {
        const int n = n0 + kgrp * 4 + q;
        cntq[q] = (n < N) ? (float)(start[n + 1] - start[n]) : 0.f;
    }

#pragma unroll
    for (int n = 0; n < 16; ++n) {
        const int col = n * 16 + mrow;
        f32x4 accH = {0.f, 0.f, 0.f, 0.f};
        f32x4 accS = {0.f, 0.f, 0.f, 0.f};
#pragma unroll
        for (int kk = 0; kk < 4; ++kk) {
            const f16x8 b = *(const f16x8*)&W1t[(size_t)col * F + kk * 32 + kgrp * 8];
            accH = __builtin_amdgcn_mfma_f32_16x16x32_f16(aA[0][kk], b, accH, 0, 0, 0);
            accS = __builtin_amdgcn_mfma_f32_16x16x32_f16(aA[1][kk], b, accS, 0, 0, 0);
        }
        const float bj = b1[col];
#pragma unroll
        for (int q = 0; q < 4; ++q) {
            const int row = kgrp * 4 + q;
            const int n_  = n0 + row;
            const float h  = accH[q] + bj;
            const float S1 = accS[q] + cntq[q] * bj;
            const float x1 = fmaxf(h + 0.9f * S1, 0.f);
            const float s2v = (n_ < N) ? S2[(size_t)n_ * H1 + col] : 0.f;
            const float x2 = 0.9f * (x1 + s2v) + 0.1f * h;
            s_a[w][row][col]      = (_Float16)x2;
            s_a[w][16 + row][col] = (_Float16)S1;
        }
    }

    asm volatile("s_waitcnt lgkmcnt(0)" ::: "memory");
    __builtin_amdgcn_sched_barrier(0);

    f16x8 aB[2][8];
#pragma unroll
    for (int m = 0; m < 2; ++m)
#pragma unroll
        for (int k0 = 0; k0 < 8; ++k0)
            aB[m][k0] = *(const f16x8*)&s_a[w][m * 16 + mrow][k0 * 32 + kgrp * 8];

#pragma unroll
    for (int n = 0; n < 8; ++n) {
        const int col = n * 16 + mrow;
        f32x4 accH = {0.f, 0.f, 0.f, 0.f};
        f32x4 accS = {0.f, 0.f, 0.f, 0.f};
#pragma unroll
        for (int k0 = 0; k0 < 8; ++k0) {
            const f16x8 b = *(const f16x8*)&W2t[(size_t)col * H1 + k0 * 32 + kgrp * 8];
            accH = __builtin_amdgcn_mfma_f32_16x16x32_f16(aB[0][k0], b, accH, 0, 0, 0);
            accS = __builtin_amdgcn_mfma_f32_16x16x32_f16(aB[1][k0], b, accS, 0, 0, 0);
        }
        const float bj = b2[col];
#pragma unroll
        for (int q = 0; q < 4; ++q) {
            const int row = kgrp * 4 + q;
            const int n_  = n0 + row;
            const float h2 = accH[q] + bj;
            const float S3 = accS[q] + cntq[q] * bj;
            const float x3 = fmaxf(h2 + 0.9f * S3, 0.f);
            const float s4v = (n_ < N) ? S4[(size_t)n_ * H2 + col] : 0.f;
            s_a[w][row][col] = (_Float16)(0.9f * (x3 + s4v) + 0.1f * h2);
        }
    }

    asm volatile("s_waitcnt lgkmcnt(0)" ::: "memory");
    __builtin_amdgcn_sched_barrier(0);

    f16x8 aC[4];
#pragma unroll
    for (int kk = 0; kk < 4; ++kk)
        aC[kk] = *(const f16x8*)&s_a[w][mrow][kk * 32 + kgrp * 8];

#pragma unroll
    for (int n = 0; n < 3; ++n) {
        const int col = n * 16 + mrow;
        f32x4 acc = {0.f, 0.f, 0.f, 0.f};
#pragma unroll
        for (int kk = 0; kk < 4; ++kk) {
            const f16x8 b = *(const f16x8*)&Wct[(size_t)col * F + kk * 32 + kgrp * 8];
            acc = __builtin_amdgcn_mfma_f32_16x16x32_f16(aC[kk], b, acc, 0, 0, 0);
        }
        if (col < C) {
            const float bcc = bc[col];
#pragma unroll
            for (int q = 0; q < 4; ++q) {
                const int n_ = n0 + kgrp * 4 + q;
                if (n_ < N) out[(size_t)n_ * C + col] = acc[q] + bcc;
            }
        }
    }
}

extern "C" void kernel_launch(void* const* d_in, const int* in_sizes, int n_in,
                              void* d_out, int out_size, void* d_ws, size_t ws_size,
                              hipStream_t stream) {
    const float* x   = (const float*)d_in[0];
    const float* nbx = (const float*)d_in[1];
    const float* W1  = (const float*)d_in[2];
    const float* b1  = (const float*)d_in[3];
    const float* W2  = (const float*)d_in[4];
    const float* b2  = (const float*)d_in[5];
    const float* Wc  = (const float*)d_in[6];
    const float* bc  = (const float*)d_in[7];
    const int*   seg = (const int*)d_in[8];

    const int N = in_sizes[0] / F;   // 50000
    const int E = in_sizes[8];       // 600000
    float* out = (float*)d_out;

    float* Sx    = (float*)d_ws;
    float* S2    = Sx + (size_t)N * F;
    float* S4    = S2 + (size_t)N * H1;
    int*   hist  = (int*)(S4 + (size_t)N * H2);
    int*   cursor= hist + N;
    int*   bsum  = cursor + N;
    int*   start = bsum + 256;
    int*   ord   = start + (N + 1);
    char*  wrest = (char*)(ord + E);
    _Float16* W1t = (_Float16*)(((uintptr_t)wrest + 15) & ~(uintptr_t)15);
    _Float16* W2t = W1t + (size_t)H1 * F;
    _Float16* Wct = W2t + (size_t)H2 * H1;

    const size_t zero_bytes = ((size_t)N * (F + H1 + H2)) * 4 + (size_t)N * 8 + 1024;
    hipMemsetAsync(d_ws, 0, zero_bytes, stream);

    prep_weights<<<128, 256, 0, stream>>>(W1, W2, Wc, W1t, W2t, Wct);

    const int B = (N + 255) / 256;
    k_hist   <<<(E + 255) / 256, 256, 0, stream>>>(seg, hist, E);
    k_scan1  <<<B, 256, 0, stream>>>(hist, bsum, N);
    k_scan2  <<<1, 256, 0, stream>>>(bsum, B);
    k_scan3  <<<B, 256, 0, stream>>>(hist, bsum, start, cursor, N, E);
    k_scatter<<<(E + 255) / 256, 256, 0, stream>>>(seg, start, cursor, ord, E);

    edge_kernel13<<<(E + 95) / 96, 256, 0, stream>>>(
        nbx, seg, ord, start, W1t, b1, W2t, b2, Sx, S2, S4, E);
    node_kernel8<<<(N + 63) / 64, 256, 0, stream>>>(
        x, W1t, b1, W2t, b2, Wct, bc, Sx, S2, S4, start, out, N);
}

// Round 14
// 598.898 us; speedup vs baseline: 1.0616x; 1.0616x over previous
//
#include <hip/hip_runtime.h>

constexpr int F  = 128;   // input feature dim
constexpr int H1 = 256;
constexpr int H2 = 128;
constexpr int C  = 40;

using f32x4 = __attribute__((ext_vector_type(4))) float;
using f16x8 = __attribute__((ext_vector_type(8))) _Float16;
using f16x2 = __attribute__((ext_vector_type(2))) _Float16;

__device__ __forceinline__ float wave_sum64(float v) {
#pragma unroll
    for (int off = 32; off > 0; off >>= 1) v += __shfl_xor(v, off, 64);
    return v;
}

// ---------------------------------------------------------------------------
// Fused prep: histogram of segment ids + weight transpose/f16 conversion.
// Grid covers E for hist; first 32768 threads also do weight prep.
// ---------------------------------------------------------------------------
__global__ __launch_bounds__(256) void k_prep_hist(
    const int* __restrict__ seg, int* __restrict__ hist, int E,
    const float* __restrict__ W1, const float* __restrict__ W2,
    const float* __restrict__ Wc,
    _Float16* __restrict__ W1t, _Float16* __restrict__ W2t,
    _Float16* __restrict__ Wct)
{
    const int i = blockIdx.x * 256 + threadIdx.x;
    if (i < E) atomicAdd(&hist[seg[i]], 1);
    if (i < H1 * F) {
        const int j = i >> 7, f = i & 127;
        W1t[i] = (_Float16)W1[(size_t)f * H1 + j];
    }
    if (i < H2 * H1) {
        const int j = i >> 8, k = i & 255;
        W2t[i] = (_Float16)W2[(size_t)k * H2 + j];
    }
    if (i < 48 * F) {
        const int c = i >> 7, k = i & 127;
        Wct[i] = (c < C) ? (_Float16)Wc[(size_t)k * C + c] : (_Float16)0.f;
    }
}

// ---------------------------------------------------------------------------
// Single-block exclusive scan over hist[N] -> start[N+1]; zeroes cursor.
// 1024 threads; thread t serially sums its chunk, block-scan of partials,
// then writes per-element prefixes. N=50k -> ~49 elems/thread, L2-resident.
// ---------------------------------------------------------------------------
__global__ __launch_bounds__(1024) void k_scan(
    const int* __restrict__ hist, int* __restrict__ start,
    int* __restrict__ cursor, int N, int E)
{
    __shared__ int s[1024];
    const int t     = threadIdx.x;
    const int chunk = (N + 1023) / 1024;
    const int lo    = t * chunk;
    const int hi    = min(lo + chunk, N);

    int sum = 0;
    for (int i = lo; i < hi; ++i) sum += hist[i];
    s[t] = sum;
    __syncthreads();

#pragma unroll
    for (int off = 1; off < 1024; off <<= 1) {
        const int u = (t >= off) ? s[t - off] : 0;
        __syncthreads();
        s[t] += u;
        __syncthreads();
    }
    int run = s[t] - sum;   // exclusive prefix of this chunk

    for (int i = lo; i < hi; ++i) {
        const int h = hist[i];
        start[i]  = run;
        cursor[i] = 0;
        run += h;
    }
    if (t == 1023) start[N] = E;
}

__global__ __launch_bounds__(256) void k_scatter(
    const int* __restrict__ seg, const int* __restrict__ start,
    int* __restrict__ cursor, int* __restrict__ ord, int E)
{
    const int e = blockIdx.x * 256 + threadIdx.x;
    if (e < E) {
        const int s = seg[e];
        const int r = atomicAdd(&cursor[s], 1);
        ord[start[s] + r] = e;
    }
}

// ---------------------------------------------------------------------------
// Edge kernel v9 (FROZEN — proven best at ~334 us):
// 2 tiles x 64 edges per block, prologue-pipelined gather, dual LDS buffers,
// column-split GEMMs, register Sx agg, f16x2 S2/S4 agg.
// r10/r11: register hoisting spills at ~84 VGPR (FETCH +90MB, 1.3-1.7x slow).
// r13: smaller agg windows triple boundary atomics (WRITE +254MB, 1.4x slow).
// ---------------------------------------------------------------------------
__global__ __launch_bounds__(256, 3) void edge_kernel9(
    const float* __restrict__ nbx, const int* __restrict__ seg,
    const int* __restrict__ ord, const int* __restrict__ start,
    const _Float16* __restrict__ W1t, const float* __restrict__ b1,
    const _Float16* __restrict__ W2t, const float* __restrict__ b2,
    float* __restrict__ Sx, float* __restrict__ S2, float* __restrict__ S4,
    int E)
{
    __shared__ _Float16 s_nb[64][136];   // nb, later n_h2
    __shared__ _Float16 s_nh[64][264];   // n_h

    const int tid   = threadIdx.x;
    const int lane  = tid & 63;
    const int w     = tid >> 6;
    const int wrow0 = w * 16;
    const int mrow  = lane & 15;
    const int kgrp  = lane >> 4;
    const int base  = blockIdx.x * 128;

    // ---- prologue: meta + gathers for both tiles ----
    int edg[2], sv[2], fl[2];
    float va[2][16][2];
#pragma unroll
    for (int t = 0; t < 2; ++t) {
        const int wbase = base + t * 64 + wrow0;
        const int p     = wbase + mrow;
        const bool pin  = (p < E);
        edg[t] = pin ? ord[p] : 0;
        sv[t]  = pin ? seg[edg[t]] : -1;
        fl[t]  = 0;
        if (pin) {
            const int s0 = start[sv[t]], s1 = start[sv[t] + 1];
            fl[t] = (s0 >= wbase) && (s1 <= wbase + 16);
        }
#pragma unroll
        for (int r = 0; r < 16; ++r) {
            const int er = __shfl(edg[t], r);
            const bool v = (wbase + r < E);
            va[t][r][0] = v ? nbx[(size_t)er * F + lane] : 0.f;
            va[t][r][1] = v ? nbx[(size_t)er * F + 64 + lane] : 0.f;
        }
    }

#pragma unroll
    for (int t = 0; t < 2; ++t) {
        // ---- l2norm + LDS store ----
#pragma unroll
        for (int r = 0; r < 16; ++r) {
            const float ss = wave_sum64(va[t][r][0] * va[t][r][0] +
                                        va[t][r][1] * va[t][r][1]);
            const float sc = 1.0f / fmaxf(sqrtf(ss), 1e-12f);
            va[t][r][0] *= sc; va[t][r][1] *= sc;
            s_nb[wrow0 + r][lane]      = (_Float16)va[t][r][0];
            s_nb[wrow0 + r][64 + lane] = (_Float16)va[t][r][1];
        }

        // ---- Sx agg from registers ----
        {
            float a0 = 0.f, a1v = 0.f;
            int cur = __shfl(sv[t], 0);
            int cf  = __shfl(fl[t], 0);
#pragma unroll
            for (int r = 0; r < 16; ++r) {
                a0 += va[t][r][0]; a1v += va[t][r][1];
                const int nxt = (r < 15) ? __shfl(sv[t], r + 1) : -2;
                if (nxt != cur) {
                    if (cur >= 0) {
                        float* d = &Sx[(size_t)cur * F + lane];
                        if (cf) { d[0] = a0; d[64] = a1v; }
                        else    { atomicAdd(d, a0); atomicAdd(d + 64, a1v); }
                    }
                    a0 = 0.f; a1v = 0.f; cur = nxt;
                    if (r < 15) cf = __shfl(fl[t], r + 1);
                }
            }
        }
        __syncthreads();   // (1) A-tile ready

        // ---- GEMM1: cols [w*64,(w+1)*64); A re-read from s_nb ----
        {
            const int colbase = w * 64 + mrow;
            float bj1[4];
#pragma unroll
            for (int ct = 0; ct < 4; ++ct) bj1[ct] = b1[colbase + ct * 16];

            f16x8 b[4], bn[4];
#pragma unroll
            for (int kk = 0; kk < 4; ++kk)
                b[kk] = *(const f16x8*)&W1t[(size_t)colbase * F + kk * 32 + kgrp * 8];

#pragma unroll
            for (int ct = 0; ct < 4; ++ct) {
                const int col = colbase + ct * 16;
                if (ct < 3) {
#pragma unroll
                    for (int kk = 0; kk < 4; ++kk)
                        bn[kk] = *(const f16x8*)&W1t[(size_t)(col + 16) * F + kk * 32 + kgrp * 8];
                }
                f32x4 acc[4];
#pragma unroll
                for (int m = 0; m < 4; ++m) acc[m] = (f32x4){0.f, 0.f, 0.f, 0.f};
                __builtin_amdgcn_s_setprio(1);
#pragma unroll
                for (int m = 0; m < 4; ++m) {
                    f16x8 a[4];
#pragma unroll
                    for (int kk = 0; kk < 4; ++kk)
                        a[kk] = *(const f16x8*)&s_nb[m * 16 + mrow][kk * 32 + kgrp * 8];
#pragma unroll
                    for (int kk = 0; kk < 4; ++kk)
                        acc[m] = __builtin_amdgcn_mfma_f32_16x16x32_f16(a[kk], b[kk], acc[m], 0, 0, 0);
                }
                __builtin_amdgcn_s_setprio(0);
#pragma unroll
                for (int m = 0; m < 4; ++m)
#pragma unroll
                    for (int q = 0; q < 4; ++q)
                        s_nh[m * 16 + kgrp * 4 + q][col] = (_Float16)(acc[m][q] + bj1[ct]);
#pragma unroll
                for (int kk = 0; kk < 4; ++kk) b[kk] = bn[kk];
            }
        }
        __syncthreads();   // (2) n_h ready

        // ---- S2 agg (own window rows of s_nh; relu on read) ----
#pragma unroll
        for (int half = 0; half < 2; ++half) {
            const int c0 = half * 128 + 2 * lane;
            float a0 = 0.f, a1v = 0.f;
            int cur = __shfl(sv[t], 0);
            int cf  = __shfl(fl[t], 0);
#pragma unroll
            for (int r = 0; r < 16; ++r) {
                const f16x2 pv = *(const f16x2*)&s_nh[wrow0 + r][c0];
                a0  += fmaxf((float)pv[0], 0.f);
                a1v += fmaxf((float)pv[1], 0.f);
                const int nxt = (r < 15) ? __shfl(sv[t], r + 1) : -2;
                if (nxt != cur) {
                    if (cur >= 0) {
                        float* d = &S2[(size_t)cur * H1 + c0];
                        if (cf) { *(float2*)d = make_float2(a0, a1v); }
                        else    { atomicAdd(d, a0); atomicAdd(d + 1, a1v); }
                    }
                    a0 = 0.f; a1v = 0.f; cur = nxt;
                    if (r < 15) cf = __shfl(fl[t], r + 1);
                }
            }
        }

        // ---- GEMM2: cols [w*32,(w+1)*32); A from s_nh; n_h2 -> s_nb ----
#pragma unroll
        for (int ct = 0; ct < 2; ++ct) {
            const int col = w * 32 + ct * 16 + mrow;
            const float bj = b2[col];
            f16x8 b[8];
#pragma unroll
            for (int k0 = 0; k0 < 8; ++k0)
                b[k0] = *(const f16x8*)&W2t[(size_t)col * H1 + k0 * 32 + kgrp * 8];
            f32x4 acc[4];
#pragma unroll
            for (int m = 0; m < 4; ++m) acc[m] = (f32x4){0.f, 0.f, 0.f, 0.f};
            __builtin_amdgcn_s_setprio(1);
#pragma unroll
            for (int m = 0; m < 4; ++m) {
                f16x8 a[8];
#pragma unroll
                for (int k0 = 0; k0 < 8; ++k0)
                    a[k0] = *(const f16x8*)&s_nh[m * 16 + mrow][k0 * 32 + kgrp * 8];
#pragma unroll
                for (int k0 = 0; k0 < 8; ++k0)
                    acc[m] = __builtin_amdgcn_mfma_f32_16x16x32_f16(a[k0], b[k0], acc[m], 0, 0, 0);
            }
            __builtin_amdgcn_s_setprio(0);
#pragma unroll
            for (int m = 0; m < 4; ++m)
#pragma unroll
                for (int q = 0; q < 4; ++q)
                    s_nb[m * 16 + kgrp * 4 + q][col] = (_Float16)(acc[m][q] + bj);
        }
        __syncthreads();   // (3) n_h2 ready

        // ---- S4 agg (own window rows of s_nb; relu on read) ----
        {
            const int c0 = 2 * lane;
            float a0 = 0.f, a1v = 0.f;
            int cur = __shfl(sv[t], 0);
            int cf  = __shfl(fl[t], 0);
#pragma unroll
            for (int r = 0; r < 16; ++r) {
                const f16x2 pv = *(const f16x2*)&s_nb[wrow0 + r][c0];
                a0  += fmaxf((float)pv[0], 0.f);
                a1v += fmaxf((float)pv[1], 0.f);
                const int nxt = (r < 15) ? __shfl(sv[t], r + 1) : -2;
                if (nxt != cur) {
                    if (cur >= 0) {
                        float* d = &S4[(size_t)cur * H2 + c0];
                        if (cf) { *(float2*)d = make_float2(a0, a1v); }
                        else    { atomicAdd(d, a0); atomicAdd(d + 1, a1v); }
                    }
                    a0 = 0.f; a1v = 0.f; cur = nxt;
                    if (r < 15) cf = __shfl(fl[t], r + 1);
                }
            }
        }
        __syncthreads();   // (4) buffers free for next tile
    }
}

// ---------------------------------------------------------------------------
// Node kernel v8 (unchanged): direct-global A-frags, MFMA, zero barriers.
// ---------------------------------------------------------------------------
__global__ __launch_bounds__(256, 2) void node_kernel8(
    const float* __restrict__ x,
    const _Float16* __restrict__ W1t, const float* __restrict__ b1,
    const _Float16* __restrict__ W2t, const float* __restrict__ b2,
    const _Float16* __restrict__ Wct, const float* __restrict__ bc,
    const float* __restrict__ Sx, const float* __restrict__ S2,
    const float* __restrict__ S4, const int* __restrict__ start,
    float* __restrict__ out, int N)
{
    __shared__ _Float16 s_a[4][32][264];

    const int tid  = threadIdx.x;
    const int lane = tid & 63;
    const int w    = tid >> 6;
    const int n0   = blockIdx.x * 64 + w * 16;
    const int mrow = lane & 15;
    const int kgrp = lane >> 4;

    const int  n_row = n0 + mrow;
    const bool rin   = (n_row < N);
    float xv[4][8], sxv[4][8];
#pragma unroll
    for (int kk = 0; kk < 4; ++kk) {
        const size_t off = (size_t)n_row * F + kk * 32 + kgrp * 8;
        float4 a0 = {0.f,0.f,0.f,0.f}, a1 = a0, b0 = a0, b1 = a0;
        if (rin) {
            a0 = *(const float4*)&x[off];
            a1 = *(const float4*)&x[off + 4];
            b0 = *(const float4*)&Sx[off];
            b1 = *(const float4*)&Sx[off + 4];
        }
        xv[kk][0]=a0.x; xv[kk][1]=a0.y; xv[kk][2]=a0.z; xv[kk][3]=a0.w;
        xv[kk][4]=a1.x; xv[kk][5]=a1.y; xv[kk][6]=a1.z; xv[kk][7]=a1.w;
        sxv[kk][0]=b0.x; sxv[kk][1]=b0.y; sxv[kk][2]=b0.z; sxv[kk][3]=b0.w;
        sxv[kk][4]=b1.x; sxv[kk][5]=b1.y; sxv[kk][6]=b1.z; sxv[kk][7]=b1.w;
    }

    float ss = 0.f;
#pragma unroll
    for (int kk = 0; kk < 4; ++kk)
#pragma unroll
        for (int j = 0; j < 8; ++j) ss += xv[kk][j] * xv[kk][j];
    ss += __shfl_xor(ss, 16);
    ss += __shfl_xor(ss, 32);
    const float sc = 1.0f / fmaxf(sqrtf(ss), 1e-12f);

    f16x8 aA[2][4];
#pragma unroll
    for (int kk = 0; kk < 4; ++kk)
#pragma unroll
        for (int j = 0; j < 8; ++j) {
            aA[0][kk][j] = (_Float16)(xv[kk][j] * sc);
            aA[1][kk][j] = (_Float16)sxv[kk][j];
        }

    float cntq[4];
#pragma unroll
    for (int q = 0; q < 4; ++q) {
        const int n = n0 + kgrp * 4 + q;
        cntq[q] = (n < N) ? (float)(start[n + 1] - start[n]) : 0.f;
    }

#pragma unroll
    for (int n = 0; n < 16; ++n) {
        const int col = n * 16 + mrow;
        f32x4 accH = {0.f, 0.f, 0.f, 0.f};
        f32x4 accS = {0.f, 0.f, 0.f, 0.f};
#pragma unroll
        for (int kk = 0; kk < 4; ++kk) {
            const f16x8 b = *(const f16x8*)&W1t[(size_t)col * F + kk * 32 + kgrp * 8];
            accH = __builtin_amdgcn_mfma_f32_16x16x32_f16(aA[0][kk], b, accH, 0, 0, 0);
            accS = __builtin_amdgcn_mfma_f32_16x16x32_f16(aA[1][kk], b, accS, 0, 0, 0);
        }
        const float bj = b1[col];
#pragma unroll
        for (int q = 0; q < 4; ++q) {
            const int row = kgrp * 4 + q;
            const int n_  = n0 + row;
            const float h  = accH[q] + bj;
            const float S1 = accS[q] + cntq[q] * bj;
            const float x1 = fmaxf(h + 0.9f * S1, 0.f);
            const float s2v = (n_ < N) ? S2[(size_t)n_ * H1 + col] : 0.f;
            const float x2 = 0.9f * (x1 + s2v) + 0.1f * h;
            s_a[w][row][col]      = (_Float16)x2;
            s_a[w][16 + row][col] = (_Float16)S1;
        }
    }

    asm volatile("s_waitcnt lgkmcnt(0)" ::: "memory");
    __builtin_amdgcn_sched_barrier(0);

    f16x8 aB[2][8];
#pragma unroll
    for (int m = 0; m < 2; ++m)
#pragma unroll
        for (int k0 = 0; k0 < 8; ++k0)
            aB[m][k0] = *(const f16x8*)&s_a[w][m * 16 + mrow][k0 * 32 + kgrp * 8];

#pragma unroll
    for (int n = 0; n < 8; ++n) {
        const int col = n * 16 + mrow;
        f32x4 accH = {0.f, 0.f, 0.f, 0.f};
        f32x4 accS = {0.f, 0.f, 0.f, 0.f};
#pragma unroll
        for (int k0 = 0; k0 < 8; ++k0) {
            const f16x8 b = *(const f16x8*)&W2t[(size_t)col * H1 + k0 * 32 + kgrp * 8];
            accH = __builtin_amdgcn_mfma_f32_16x16x32_f16(aB[0][k0], b, accH, 0, 0, 0);
            accS = __builtin_amdgcn_mfma_f32_16x16x32_f16(aB[1][k0], b, accS, 0, 0, 0);
        }
        const float bj = b2[col];
#pragma unroll
        for (int q = 0; q < 4; ++q) {
            const int row = kgrp * 4 + q;
            const int n_  = n0 + row;
            const float h2 = accH[q] + bj;
            const float S3 = accS[q] + cntq[q] * bj;
            const float x3 = fmaxf(h2 + 0.9f * S3, 0.f);
            const float s4v = (n_ < N) ? S4[(size_t)n_ * H2 + col] : 0.f;
            s_a[w][row][col] = (_Float16)(0.9f * (x3 + s4v) + 0.1f * h2);
        }
    }

    asm volatile("s_waitcnt lgkmcnt(0)" ::: "memory");
    __builtin_amdgcn_sched_barrier(0);

    f16x8 aC[4];
#pragma unroll
    for (int kk = 0; kk < 4; ++kk)
        aC[kk] = *(const f16x8*)&s_a[w][mrow][kk * 32 + kgrp * 8];

#pragma unroll
    for (int n = 0; n < 3; ++n) {
        const int col = n * 16 + mrow;
        f32x4 acc = {0.f, 0.f, 0.f, 0.f};
#pragma unroll
        for (int kk = 0; kk < 4; ++kk) {
            const f16x8 b = *(const f16x8*)&Wct[(size_t)col * F + kk * 32 + kgrp * 8];
            acc = __builtin_amdgcn_mfma_f32_16x16x32_f16(aC[kk], b, acc, 0, 0, 0);
        }
        if (col < C) {
            const float bcc = bc[col];
#pragma unroll
            for (int q = 0; q < 4; ++q) {
                const int n_ = n0 + kgrp * 4 + q;
                if (n_ < N) out[(size_t)n_ * C + col] = acc[q] + bcc;
            }
        }
    }
}

extern "C" void kernel_launch(void* const* d_in, const int* in_sizes, int n_in,
                              void* d_out, int out_size, void* d_ws, size_t ws_size,
                              hipStream_t stream) {
    const float* x   = (const float*)d_in[0];
    const float* nbx = (const float*)d_in[1];
    const float* W1  = (const float*)d_in[2];
    const float* b1  = (const float*)d_in[3];
    const float* W2  = (const float*)d_in[4];
    const float* b2  = (const float*)d_in[5];
    const float* Wc  = (const float*)d_in[6];
    const float* bc  = (const float*)d_in[7];
    const int*   seg = (const int*)d_in[8];

    const int N = in_sizes[0] / F;   // 50000
    const int E = in_sizes[8];       // 600000
    float* out = (float*)d_out;

    // workspace: [Sx | S2 | S4 | hist] <- zeroed ; [cursor | start | ord | W*t]
    float* Sx    = (float*)d_ws;
    float* S2    = Sx + (size_t)N * F;
    float* S4    = S2 + (size_t)N * H1;
    int*   hist  = (int*)(S4 + (size_t)N * H2);
    int*   cursor= hist + N;
    int*   start = cursor + N;
    int*   ord   = start + (N + 1);
    char*  wrest = (char*)(ord + E);
    _Float16* W1t = (_Float16*)(((uintptr_t)wrest + 15) & ~(uintptr_t)15);
    _Float16* W2t = W1t + (size_t)H1 * F;
    _Float16* Wct = W2t + (size_t)H2 * H1;

    const size_t zero_bytes = ((size_t)N * (F + H1 + H2)) * 4 + (size_t)N * 4;
    hipMemsetAsync(d_ws, 0, zero_bytes, stream);

    k_prep_hist<<<(E + 255) / 256, 256, 0, stream>>>(
        seg, hist, E, W1, W2, Wc, W1t, W2t, Wct);
    k_scan   <<<1, 1024, 0, stream>>>(hist, start, cursor, N, E);
    k_scatter<<<(E + 255) / 256, 256, 0, stream>>>(seg, start, cursor, ord, E);

    edge_kernel9<<<(E + 127) / 128, 256, 0, stream>>>(
        nbx, seg, ord, start, W1t, b1, W2t, b2, Sx, S2, S4, E);
    node_kernel8<<<(N + 63) / 64, 256, 0, stream>>>(
        x, W1t, b1, W2t, b2, Wct, bc, Sx, S2, S4, start, out, N);
}

// Round 15
// 503.160 us; speedup vs baseline: 1.2636x; 1.1903x over previous
//
#include <hip/hip_runtime.h>

constexpr int F  = 128;   // input feature dim
constexpr int H1 = 256;
constexpr int H2 = 128;
constexpr int C  = 40;

using f32x4 = __attribute__((ext_vector_type(4))) float;
using f16x8 = __attribute__((ext_vector_type(8))) _Float16;
using f16x2 = __attribute__((ext_vector_type(2))) _Float16;

__device__ __forceinline__ float wave_sum64(float v) {
#pragma unroll
    for (int off = 32; off > 0; off >>= 1) v += __shfl_xor(v, off, 64);
    return v;
}

// ---------------------------------------------------------------------------
// Weight prep: transpose + fp16-convert W1, W2, Wc into workspace.
// ---------------------------------------------------------------------------
__global__ __launch_bounds__(256) void prep_weights(
    const float* __restrict__ W1, const float* __restrict__ W2,
    const float* __restrict__ Wc,
    _Float16* __restrict__ W1t, _Float16* __restrict__ W2t,
    _Float16* __restrict__ Wct)
{
    const int i = blockIdx.x * 256 + threadIdx.x;
    if (i < H1 * F) {
        const int j = i >> 7, f = i & 127;
        W1t[i] = (_Float16)W1[(size_t)f * H1 + j];
    }
    if (i < H2 * H1) {
        const int j = i >> 8, k = i & 255;
        W2t[i] = (_Float16)W2[(size_t)k * H2 + j];
    }
    if (i < 48 * F) {
        const int c = i >> 7, k = i & 127;
        Wct[i] = (c < C) ? (_Float16)Wc[(size_t)k * C + c] : (_Float16)0.f;
    }
}

// ---------------------------------------------------------------------------
// Counting sort of edges by segment: hist -> 3-pass scan -> scatter.
// (r14 post-mortem: single-block scan + fused prep regressed +96 us — the
// parallel 3-kernel scan chain below is the proven-fast form. Keep it.)
// ---------------------------------------------------------------------------
__global__ __launch_bounds__(256) void k_hist(
    const int* __restrict__ seg, int* __restrict__ hist, int E)
{
    const int e = blockIdx.x * 256 + threadIdx.x;
    if (e < E) atomicAdd(&hist[seg[e]], 1);
}

__global__ __launch_bounds__(256) void k_scan1(
    const int* __restrict__ hist, int* __restrict__ bsum, int N)
{
    __shared__ int s[256];
    const int t = threadIdx.x;
    const int i = blockIdx.x * 256 + t;
    s[t] = (i < N) ? hist[i] : 0;
    __syncthreads();
#pragma unroll
    for (int off = 128; off > 0; off >>= 1) {
        if (t < off) s[t] += s[t + off];
        __syncthreads();
    }
    if (t == 0) bsum[blockIdx.x] = s[0];
}

__global__ __launch_bounds__(256) void k_scan2(int* __restrict__ bsum, int B)
{
    __shared__ int s[256];
    const int t = threadIdx.x;
    const int v = (t < B) ? bsum[t] : 0;
    s[t] = v;
    __syncthreads();
#pragma unroll
    for (int off = 1; off < 256; off <<= 1) {
        const int u = (t >= off) ? s[t - off] : 0;
        __syncthreads();
        s[t] += u;
        __syncthreads();
    }
    if (t < B) bsum[t] = s[t] - v;   // exclusive block offsets
}

__global__ __launch_bounds__(256) void k_scan3(
    const int* __restrict__ hist, const int* __restrict__ bsum,
    int* __restrict__ start, int* __restrict__ cursor, int N, int E)
{
    __shared__ int s[256];
    const int t = threadIdx.x;
    const int i = blockIdx.x * 256 + t;
    const int v = (i < N) ? hist[i] : 0;
    s[t] = v;
    __syncthreads();
#pragma unroll
    for (int off = 1; off < 256; off <<= 1) {
        const int u = (t >= off) ? s[t - off] : 0;
        __syncthreads();
        s[t] += u;
        __syncthreads();
    }
    if (i < N) {
        start[i]  = bsum[blockIdx.x] + s[t] - v;
        cursor[i] = 0;
    }
    if (i == 0) start[N] = E;
}

__global__ __launch_bounds__(256) void k_scatter(
    const int* __restrict__ seg, const int* __restrict__ start,
    int* __restrict__ cursor, int* __restrict__ ord, int E)
{
    const int e = blockIdx.x * 256 + threadIdx.x;
    if (e < E) {
        const int s = seg[e];
        const int r = atomicAdd(&cursor[s], 1);
        ord[start[s] + r] = e;
    }
}

// ---------------------------------------------------------------------------
// Edge kernel v9 (FROZEN — proven best at ~334 us):
// 2 tiles x 64 edges per block, prologue-pipelined gather, dual LDS buffers,
// column-split GEMMs, register Sx agg, f16x2 S2/S4 agg.
// r10/r11: register hoisting spills at ~84 VGPR (FETCH +90MB, 1.3-1.7x slow).
// r13: smaller agg windows triple boundary atomics (WRITE +254MB, 1.4x slow).
// ---------------------------------------------------------------------------
__global__ __launch_bounds__(256, 3) void edge_kernel9(
    const float* __restrict__ nbx, const int* __restrict__ seg,
    const int* __restrict__ ord, const int* __restrict__ start,
    const _Float16* __restrict__ W1t, const float* __restrict__ b1,
    const _Float16* __restrict__ W2t, const float* __restrict__ b2,
    float* __restrict__ Sx, float* __restrict__ S2, float* __restrict__ S4,
    int E)
{
    __shared__ _Float16 s_nb[64][136];   // nb, later n_h2
    __shared__ _Float16 s_nh[64][264];   // n_h

    const int tid   = threadIdx.x;
    const int lane  = tid & 63;
    const int w     = tid >> 6;
    const int wrow0 = w * 16;
    const int mrow  = lane & 15;
    const int kgrp  = lane >> 4;
    const int base  = blockIdx.x * 128;

    // ---- prologue: meta + gathers for both tiles ----
    int edg[2], sv[2], fl[2];
    float va[2][16][2];
#pragma unroll
    for (int t = 0; t < 2; ++t) {
        const int wbase = base + t * 64 + wrow0;
        const int p     = wbase + mrow;
        const bool pin  = (p < E);
        edg[t] = pin ? ord[p] : 0;
        sv[t]  = pin ? seg[edg[t]] : -1;
        fl[t]  = 0;
        if (pin) {
            const int s0 = start[sv[t]], s1 = start[sv[t] + 1];
            fl[t] = (s0 >= wbase) && (s1 <= wbase + 16);
        }
#pragma unroll
        for (int r = 0; r < 16; ++r) {
            const int er = __shfl(edg[t], r);
            const bool v = (wbase + r < E);
            va[t][r][0] = v ? nbx[(size_t)er * F + lane] : 0.f;
            va[t][r][1] = v ? nbx[(size_t)er * F + 64 + lane] : 0.f;
        }
    }

#pragma unroll
    for (int t = 0; t < 2; ++t) {
        // ---- l2norm + LDS store ----
#pragma unroll
        for (int r = 0; r < 16; ++r) {
            const float ss = wave_sum64(va[t][r][0] * va[t][r][0] +
                                        va[t][r][1] * va[t][r][1]);
            const float sc = 1.0f / fmaxf(sqrtf(ss), 1e-12f);
            va[t][r][0] *= sc; va[t][r][1] *= sc;
            s_nb[wrow0 + r][lane]      = (_Float16)va[t][r][0];
            s_nb[wrow0 + r][64 + lane] = (_Float16)va[t][r][1];
        }

        // ---- Sx agg from registers ----
        {
            float a0 = 0.f, a1v = 0.f;
            int cur = __shfl(sv[t], 0);
            int cf  = __shfl(fl[t], 0);
#pragma unroll
            for (int r = 0; r < 16; ++r) {
                a0 += va[t][r][0]; a1v += va[t][r][1];
                const int nxt = (r < 15) ? __shfl(sv[t], r + 1) : -2;
                if (nxt != cur) {
                    if (cur >= 0) {
                        float* d = &Sx[(size_t)cur * F + lane];
                        if (cf) { d[0] = a0; d[64] = a1v; }
                        else    { atomicAdd(d, a0); atomicAdd(d + 64, a1v); }
                    }
                    a0 = 0.f; a1v = 0.f; cur = nxt;
                    if (r < 15) cf = __shfl(fl[t], r + 1);
                }
            }
        }
        __syncthreads();   // (1) A-tile ready

        // ---- GEMM1: cols [w*64,(w+1)*64); A re-read from s_nb ----
        {
            const int colbase = w * 64 + mrow;
            float bj1[4];
#pragma unroll
            for (int ct = 0; ct < 4; ++ct) bj1[ct] = b1[colbase + ct * 16];

            f16x8 b[4], bn[4];
#pragma unroll
            for (int kk = 0; kk < 4; ++kk)
                b[kk] = *(const f16x8*)&W1t[(size_t)colbase * F + kk * 32 + kgrp * 8];

#pragma unroll
            for (int ct = 0; ct < 4; ++ct) {
                const int col = colbase + ct * 16;
                if (ct < 3) {
#pragma unroll
                    for (int kk = 0; kk < 4; ++kk)
                        bn[kk] = *(const f16x8*)&W1t[(size_t)(col + 16) * F + kk * 32 + kgrp * 8];
                }
                f32x4 acc[4];
#pragma unroll
                for (int m = 0; m < 4; ++m) acc[m] = (f32x4){0.f, 0.f, 0.f, 0.f};
                __builtin_amdgcn_s_setprio(1);
#pragma unroll
                for (int m = 0; m < 4; ++m) {
                    f16x8 a[4];
#pragma unroll
                    for (int kk = 0; kk < 4; ++kk)
                        a[kk] = *(const f16x8*)&s_nb[m * 16 + mrow][kk * 32 + kgrp * 8];
#pragma unroll
                    for (int kk = 0; kk < 4; ++kk)
                        acc[m] = __builtin_amdgcn_mfma_f32_16x16x32_f16(a[kk], b[kk], acc[m], 0, 0, 0);
                }
                __builtin_amdgcn_s_setprio(0);
#pragma unroll
                for (int m = 0; m < 4; ++m)
#pragma unroll
                    for (int q = 0; q < 4; ++q)
                        s_nh[m * 16 + kgrp * 4 + q][col] = (_Float16)(acc[m][q] + bj1[ct]);
#pragma unroll
                for (int kk = 0; kk < 4; ++kk) b[kk] = bn[kk];
            }
        }
        __syncthreads();   // (2) n_h ready

        // ---- S2 agg (own window rows of s_nh; relu on read) ----
#pragma unroll
        for (int half = 0; half < 2; ++half) {
            const int c0 = half * 128 + 2 * lane;
            float a0 = 0.f, a1v = 0.f;
            int cur = __shfl(sv[t], 0);
            int cf  = __shfl(fl[t], 0);
#pragma unroll
            for (int r = 0; r < 16; ++r) {
                const f16x2 pv = *(const f16x2*)&s_nh[wrow0 + r][c0];
                a0  += fmaxf((float)pv[0], 0.f);
                a1v += fmaxf((float)pv[1], 0.f);
                const int nxt = (r < 15) ? __shfl(sv[t], r + 1) : -2;
                if (nxt != cur) {
                    if (cur >= 0) {
                        float* d = &S2[(size_t)cur * H1 + c0];
                        if (cf) { *(float2*)d = make_float2(a0, a1v); }
                        else    { atomicAdd(d, a0); atomicAdd(d + 1, a1v); }
                    }
                    a0 = 0.f; a1v = 0.f; cur = nxt;
                    if (r < 15) cf = __shfl(fl[t], r + 1);
                }
            }
        }

        // ---- GEMM2: cols [w*32,(w+1)*32); A from s_nh; n_h2 -> s_nb ----
#pragma unroll
        for (int ct = 0; ct < 2; ++ct) {
            const int col = w * 32 + ct * 16 + mrow;
            const float bj = b2[col];
            f16x8 b[8];
#pragma unroll
            for (int k0 = 0; k0 < 8; ++k0)
                b[k0] = *(const f16x8*)&W2t[(size_t)col * H1 + k0 * 32 + kgrp * 8];
            f32x4 acc[4];
#pragma unroll
            for (int m = 0; m < 4; ++m) acc[m] = (f32x4){0.f, 0.f, 0.f, 0.f};
            __builtin_amdgcn_s_setprio(1);
#pragma unroll
            for (int m = 0; m < 4; ++m) {
                f16x8 a[8];
#pragma unroll
                for (int k0 = 0; k0 < 8; ++k0)
                    a[k0] = *(const f16x8*)&s_nh[m * 16 + mrow][k0 * 32 + kgrp * 8];
#pragma unroll
                for (int k0 = 0; k0 < 8; ++k0)
                    acc[m] = __builtin_amdgcn_mfma_f32_16x16x32_f16(a[k0], b[k0], acc[m], 0, 0, 0);
            }
            __builtin_amdgcn_s_setprio(0);
#pragma unroll
            for (int m = 0; m < 4; ++m)
#pragma unroll
                for (int q = 0; q < 4; ++q)
                    s_nb[m * 16 + kgrp * 4 + q][col] = (_Float16)(acc[m][q] + bj);
        }
        __syncthreads();   // (3) n_h2 ready

        // ---- S4 agg (own window rows of s_nb; relu on read) ----
        {
            const int c0 = 2 * lane;
            float a0 = 0.f, a1v = 0.f;
            int cur = __shfl(sv[t], 0);
            int cf  = __shfl(fl[t], 0);
#pragma unroll
            for (int r = 0; r < 16; ++r) {
                const f16x2 pv = *(const f16x2*)&s_nb[wrow0 + r][c0];
                a0  += fmaxf((float)pv[0], 0.f);
                a1v += fmaxf((float)pv[1], 0.f);
                const int nxt = (r < 15) ? __shfl(sv[t], r + 1) : -2;
                if (nxt != cur) {
                    if (cur >= 0) {
                        float* d = &S4[(size_t)cur * H2 + c0];
                        if (cf) { *(float2*)d = make_float2(a0, a1v); }
                        else    { atomicAdd(d, a0); atomicAdd(d + 1, a1v); }
                    }
                    a0 = 0.f; a1v = 0.f; cur = nxt;
                    if (r < 15) cf = __shfl(fl[t], r + 1);
                }
            }
        }
        __syncthreads();   // (4) buffers free for next tile
    }
}

// ---------------------------------------------------------------------------
// Node kernel v8 (FROZEN): direct-global A-frags, MFMA, zero barriers.
// ---------------------------------------------------------------------------
__global__ __launch_bounds__(256, 2) void node_kernel8(
    const float* __restrict__ x,
    const _Float16* __restrict__ W1t, const float* __restrict__ b1,
    const _Float16* __restrict__ W2t, const float* __restrict__ b2,
    const _Float16* __restrict__ Wct, const float* __restrict__ bc,
    const float* __restrict__ Sx, const float* __restrict__ S2,
    const float* __restrict__ S4, const int* __restrict__ start,
    float* __restrict__ out, int N)
{
    __shared__ _Float16 s_a[4][32][264];

    const int tid  = threadIdx.x;
    const int lane = tid & 63;
    const int w    = tid >> 6;
    const int n0   = blockIdx.x * 64 + w * 16;
    const int mrow = lane & 15;
    const int kgrp = lane >> 4;

    const int  n_row = n0 + mrow;
    const bool rin   = (n_row < N);
    float xv[4][8], sxv[4][8];
#pragma unroll
    for (int kk = 0; kk < 4; ++kk) {
        const size_t off = (size_t)n_row * F + kk * 32 + kgrp * 8;
        float4 a0 = {0.f,0.f,0.f,0.f}, a1 = a0, b0 = a0, b1 = a0;
        if (rin) {
            a0 = *(const float4*)&x[off];
            a1 = *(const float4*)&x[off + 4];
            b0 = *(const float4*)&Sx[off];
            b1 = *(const float4*)&Sx[off + 4];
        }
        xv[kk][0]=a0.x; xv[kk][1]=a0.y; xv[kk][2]=a0.z; xv[kk][3]=a0.w;
        xv[kk][4]=a1.x; xv[kk][5]=a1.y; xv[kk][6]=a1.z; xv[kk][7]=a1.w;
        sxv[kk][0]=b0.x; sxv[kk][1]=b0.y; sxv[kk][2]=b0.z; sxv[kk][3]=b0.w;
        sxv[kk][4]=b1.x; sxv[kk][5]=b1.y; sxv[kk][6]=b1.z; sxv[kk][7]=b1.w;
    }

    float ss = 0.f;
#pragma unroll
    for (int kk = 0; kk < 4; ++kk)
#pragma unroll
        for (int j = 0; j < 8; ++j) ss += xv[kk][j] * xv[kk][j];
    ss += __shfl_xor(ss, 16);
    ss += __shfl_xor(ss, 32);
    const float sc = 1.0f / fmaxf(sqrtf(ss), 1e-12f);

    f16x8 aA[2][4];
#pragma unroll
    for (int kk = 0; kk < 4; ++kk)
#pragma unroll
        for (int j = 0; j < 8; ++j) {
            aA[0][kk][j] = (_Float16)(xv[kk][j] * sc);
            aA[1][kk][j] = (_Float16)sxv[kk][j];
        }

    float cntq[4];
#pragma unroll
    for (int q = 0; q < 4; ++q) {
        const int n = n0 + kgrp * 4 + q;
        cntq[q] = (n < N) ? (float)(start[n + 1] - start[n]) : 0.f;
    }

#pragma unroll
    for (int n = 0; n < 16; ++n) {
        const int col = n * 16 + mrow;
        f32x4 accH = {0.f, 0.f, 0.f, 0.f};
        f32x4 accS = {0.f, 0.f, 0.f, 0.f};
#pragma unroll
        for (int kk = 0; kk < 4; ++kk) {
            const f16x8 b = *(const f16x8*)&W1t[(size_t)col * F + kk * 32 + kgrp * 8];
            accH = __builtin_amdgcn_mfma_f32_16x16x32_f16(aA[0][kk], b, accH, 0, 0, 0);
            accS = __builtin_amdgcn_mfma_f32_16x16x32_f16(aA[1][kk], b, accS, 0, 0, 0);
        }
        const float bj = b1[col];
#pragma unroll
        for (int q = 0; q < 4; ++q) {
            const int row = kgrp * 4 + q;
            const int n_  = n0 + row;
            const float h  = accH[q] + bj;
            const float S1 = accS[q] + cntq[q] * bj;
            const float x1 = fmaxf(h + 0.9f * S1, 0.f);
            const float s2v = (n_ < N) ? S2[(size_t)n_ * H1 + col] : 0.f;
            const float x2 = 0.9f * (x1 + s2v) + 0.1f * h;
            s_a[w][row][col]      = (_Float16)x2;
            s_a[w][16 + row][col] = (_Float16)S1;
        }
    }

    asm volatile("s_waitcnt lgkmcnt(0)" ::: "memory");
    __builtin_amdgcn_sched_barrier(0);

    f16x8 aB[2][8];
#pragma unroll
    for (int m = 0; m < 2; ++m)
#pragma unroll
        for (int k0 = 0; k0 < 8; ++k0)
            aB[m][k0] = *(const f16x8*)&s_a[w][m * 16 + mrow][k0 * 32 + kgrp * 8];

#pragma unroll
    for (int n = 0; n < 8; ++n) {
        const int col = n * 16 + mrow;
        f32x4 accH = {0.f, 0.f, 0.f, 0.f};
        f32x4 accS = {0.f, 0.f, 0.f, 0.f};
#pragma unroll
        for (int k0 = 0; k0 < 8; ++k0) {
            const f16x8 b = *(const f16x8*)&W2t[(size_t)col * H1 + k0 * 32 + kgrp * 8];
            accH = __builtin_amdgcn_mfma_f32_16x16x32_f16(aB[0][k0], b, accH, 0, 0, 0);
            accS = __builtin_amdgcn_mfma_f32_16x16x32_f16(aB[1][k0], b, accS, 0, 0, 0);
        }
        const float bj = b2[col];
#pragma unroll
        for (int q = 0; q < 4; ++q) {
            const int row = kgrp * 4 + q;
            const int n_  = n0 + row;
            const float h2 = accH[q] + bj;
            const float S3 = accS[q] + cntq[q] * bj;
            const float x3 = fmaxf(h2 + 0.9f * S3, 0.f);
            const float s4v = (n_ < N) ? S4[(size_t)n_ * H2 + col] : 0.f;
            s_a[w][row][col] = (_Float16)(0.9f * (x3 + s4v) + 0.1f * h2);
        }
    }

    asm volatile("s_waitcnt lgkmcnt(0)" ::: "memory");
    __builtin_amdgcn_sched_barrier(0);

    f16x8 aC[4];
#pragma unroll
    for (int kk = 0; kk < 4; ++kk)
        aC[kk] = *(const f16x8*)&s_a[w][mrow][kk * 32 + kgrp * 8];

#pragma unroll
    for (int n = 0; n < 3; ++n) {
        const int col = n * 16 + mrow;
        f32x4 acc = {0.f, 0.f, 0.f, 0.f};
#pragma unroll
        for (int kk = 0; kk < 4; ++kk) {
            const f16x8 b = *(const f16x8*)&Wct[(size_t)col * F + kk * 32 + kgrp * 8];
            acc = __builtin_amdgcn_mfma_f32_16x16x32_f16(aC[kk], b, acc, 0, 0, 0);
        }
        if (col < C) {
            const float bcc = bc[col];
#pragma unroll
            for (int q = 0; q < 4; ++q) {
                const int n_ = n0 + kgrp * 4 + q;
                if (n_ < N) out[(size_t)n_ * C + col] = acc[q] + bcc;
            }
        }
    }
}

extern "C" void kernel_launch(void* const* d_in, const int* in_sizes, int n_in,
                              void* d_out, int out_size, void* d_ws, size_t ws_size,
                              hipStream_t stream) {
    const float* x   = (const float*)d_in[0];
    const float* nbx = (const float*)d_in[1];
    const float* W1  = (const float*)d_in[2];
    const float* b1  = (const float*)d_in[3];
    const float* W2  = (const float*)d_in[4];
    const float* b2  = (const float*)d_in[5];
    const float* Wc  = (const float*)d_in[6];
    const float* bc  = (const float*)d_in[7];
    const int*   seg = (const int*)d_in[8];

    const int N = in_sizes[0] / F;   // 50000
    const int E = in_sizes[8];       // 600000
    float* out = (float*)d_out;

    float* Sx    = (float*)d_ws;
    float* S2    = Sx + (size_t)N * F;
    float* S4    = S2 + (size_t)N * H1;
    int*   hist  = (int*)(S4 + (size_t)N * H2);
    int*   cursor= hist + N;
    int*   bsum  = cursor + N;
    int*   start = bsum + 256;
    int*   ord   = start + (N + 1);
    char*  wrest = (char*)(ord + E);
    _Float16* W1t = (_Float16*)(((uintptr_t)wrest + 15) & ~(uintptr_t)15);
    _Float16* W2t = W1t + (size_t)H1 * F;
    _Float16* Wct = W2t + (size_t)H2 * H1;

    const size_t zero_bytes = ((size_t)N * (F + H1 + H2)) * 4 + (size_t)N * 8 + 1024;
    hipMemsetAsync(d_ws, 0, zero_bytes, stream);

    prep_weights<<<128, 256, 0, stream>>>(W1, W2, Wc, W1t, W2t, Wct);

    const int B = (N + 255) / 256;
    k_hist   <<<(E + 255) / 256, 256, 0, stream>>>(seg, hist, E);
    k_scan1  <<<B, 256, 0, stream>>>(hist, bsum, N);
    k_scan2  <<<1, 256, 0, stream>>>(bsum, B);
    k_scan3  <<<B, 256, 0, stream>>>(hist, bsum, start, cursor, N, E);
    k_scatter<<<(E + 255) / 256, 256, 0, stream>>>(seg, start, cursor, ord, E);

    edge_kernel9<<<(E + 127) / 128, 256, 0, stream>>>(
        nbx, seg, ord, start, W1t, b1, W2t, b2, Sx, S2, S4, E);
    node_kernel8<<<(N + 63) / 64, 256, 0, stream>>>(
        x, W1t, b1, W2t, b2, Wct, bc, Sx, S2, S4, start, out, N);
}